// Round 2
// baseline (10627.298 us; speedup 1.0000x reference)
//
#include <hip/hip_runtime.h>
#include <math.h>

#define H   256
#define TT  128
#define BT  8     // batch rows per block
#define NTC 3
#define EE  8
#define PP  6

__device__ __forceinline__ float sigf(float x) { return 1.0f / (1.0f + expf(-x)); }

// ---------------- pack weights: transposed, gate-concatenated, float4-tiled ----
// wbA[(k4*2+g)*256+t] = {Uz0|Ur0}[t][4k4..+3]               (phase A, g=0:z 1:r)
// wbH[k4*256+t]       = Uh0[t][4k4..+3]                      (phase B)
// wbC[(k4*5+g)*256+t] = g<3: {Wz1,Wr1,Wh1}[t][4k4..+3]       (phase C, h0n part)
//                       g=3: Uz1[t][..] g=4: Ur1[t][..]      (phase C, h1 part)
// wbD[k4*256+t]       = Uh1[t][4k4..+3]                      (phase D)
__global__ void pack_weights(const float* __restrict__ Uz0, const float* __restrict__ Ur0, const float* __restrict__ Uh0,
                             const float* __restrict__ Wz1, const float* __restrict__ Wr1, const float* __restrict__ Wh1,
                             const float* __restrict__ Uz1, const float* __restrict__ Ur1, const float* __restrict__ Uh1,
                             float4* __restrict__ wbA, float4* __restrict__ wbH,
                             float4* __restrict__ wbC, float4* __restrict__ wbD)
{
    int idx = blockIdx.x * 256 + threadIdx.x;
    if (idx < 32768) {
        int k4 = idx >> 9; int rem = idx & 511; int g = rem >> 8; int t = rem & 255;
        const float* U = (g == 0) ? Uz0 : Ur0;
        const float* p = U + t * H + k4 * 4;
        wbA[idx] = make_float4(p[0], p[1], p[2], p[3]);
    } else if (idx < 49152) {
        int i2 = idx - 32768;
        int k4 = i2 >> 8, t = i2 & 255;
        const float* p = Uh0 + t * H + k4 * 4;
        wbH[i2] = make_float4(p[0], p[1], p[2], p[3]);
    } else if (idx < 131072) {
        int i3 = idx - 49152;                      // < 81920
        int k4 = i3 / 1280; int rem = i3 - k4 * 1280; int g = rem >> 8; int t = rem & 255;
        const float* p;
        if (g < 3) { const float* W = (g == 0) ? Wz1 : ((g == 1) ? Wr1 : Wh1); p = W + t * 264 + k4 * 4; }
        else       { const float* U = (g == 3) ? Uz1 : Ur1;                    p = U + t * H   + k4 * 4; }
        wbC[i3] = make_float4(p[0], p[1], p[2], p[3]);
    } else if (idx < 147456) {
        int i4 = idx - 131072;
        int k4 = i4 >> 8, t = i4 & 255;
        const float* p = Uh1 + t * H + k4 * 4;
        wbD[i4] = make_float4(p[0], p[1], p[2], p[3]);
    }
}

// ---------------- per-class / per-unit constant vectors -----------------------
// cst layout (floats): A0[3g][3c][256] | B1[3g][3c][256] | I0[3c][256] | I1[3c][256]
//                      | L0[3g][256] | L1[3g][256] | WC[3g][256]
__global__ void pack_consts(const float* __restrict__ Wz0, const float* __restrict__ Wr0, const float* __restrict__ Wh0,
                            const float* __restrict__ Vw0, const float* __restrict__ Vb0,
                            const float* __restrict__ lz0, const float* __restrict__ lr0, const float* __restrict__ lh0,
                            const float* __restrict__ Wz1, const float* __restrict__ Wr1, const float* __restrict__ Wh1,
                            const float* __restrict__ Vw1, const float* __restrict__ Vb1,
                            const float* __restrict__ lz1, const float* __restrict__ lr1, const float* __restrict__ lh1,
                            const float* __restrict__ emb, float* __restrict__ cst)
{
    int t = threadIdx.x;
    float* A0 = cst;         float* B1 = cst + 2304;
    float* I0 = cst + 4608;  float* I1 = cst + 5376;
    float* L0 = cst + 6144;  float* L1 = cst + 6912;
    float* WC = cst + 7680;
    const float* W0s[3] = {Wz0, Wr0, Wh0};
    const float* W1s[3] = {Wz1, Wr1, Wh1};
    const float* ls0[3] = {lz0, lr0, lh0};
    const float* ls1[3] = {lz1, lr1, lh1};
    for (int g = 0; g < 3; ++g) {
        WC[g * H + t] = W0s[g][t * 9];
        L0[g * H + t] = 0.05f + 0.45f * sigf(ls0[g][t]);
        L1[g * H + t] = 0.05f + 0.45f * sigf(ls1[g][t]);
        for (int c = 0; c < NTC; ++c) {
            float s0 = 0.f, s1 = 0.f;
            for (int e = 0; e < EE; ++e) {
                s0 += W0s[g][t * 9 + 1 + e]     * emb[c * EE + e];
                s1 += W1s[g][t * 264 + 256 + e] * emb[c * EE + e];
            }
            A0[(g * 3 + c) * H + t] = s0;
            B1[(g * 3 + c) * H + t] = s1;
        }
    }
    for (int c = 0; c < NTC; ++c) {
        float s0 = Vb0[t], s1 = Vb1[t];
        for (int e = 0; e < EE; ++e) {
            s0 += Vw0[t * EE + e] * emb[c * EE + e];
            s1 += Vw1[t * EE + e] * emb[c * EE + e];
        }
        I0[c * H + t] = s0;
        I1[c * H + t] = s1;
    }
}

// ---------------- persistent scan: 1 block = 8 batch rows, all 128 steps ------
__global__ __launch_bounds__(256) void trs_scan(
    const float* __restrict__ x,
    const float4* __restrict__ wbA, const float4* __restrict__ wbH,
    const float4* __restrict__ wbC, const float4* __restrict__ wbD,
    const float* __restrict__ cst, const float* __restrict__ fcw, const float* __restrict__ fcb,
    float* __restrict__ out)
{
    __shared__ __align__(16) float h0[BT][H];
    __shared__ __align__(16) float h1[BT][H];
    __shared__ __align__(16) float rh0[BT][H];
    __shared__ __align__(16) float rh1[BT][H];
    __shared__ float xm[BT][TT];
    __shared__ int   xcls[BT][TT];

    const int t  = threadIdx.x;
    const int r0 = blockIdx.x * BT;

    // preload per-thread constants (hidden unit t)
    const float* A0 = cst;         const float* B1 = cst + 2304;
    const float* I0 = cst + 4608;  const float* I1 = cst + 5376;
    const float* L0 = cst + 6144;  const float* L1 = cst + 6912;
    const float* WC = cst + 7680;
    float az[3][3], b1c[3][3], i0v[3], i1v[3], l0[3], l1[3], wc[3];
    for (int g = 0; g < 3; ++g) {
        wc[g] = WC[g * H + t]; l0[g] = L0[g * H + t]; l1[g] = L1[g * H + t];
        for (int c = 0; c < 3; ++c) {
            az[g][c]  = A0[(g * 3 + c) * H + t];
            b1c[g][c] = B1[(g * 3 + c) * H + t];
        }
    }
    for (int c = 0; c < 3; ++c) { i0v[c] = I0[c * H + t]; i1v[c] = I1[c * H + t]; }

    // stage x for this block's rows; init states
    for (int i = t; i < BT * TT; i += 256) {
        int b = i >> 7, tt = i & 127;
        float2 v = *(const float2*)(x + ((size_t)(r0 + b) * TT + tt) * 2);
        xm[b][tt] = v.x;
        int c = (int)v.y; c = c < 0 ? 0 : (c > 2 ? 2 : c);
        xcls[b][tt] = c;
    }
    for (int b = 0; b < BT; ++b) { h0[b][t] = 0.f; h1[b][t] = 0.f; }
    __syncthreads();

    for (int step = 0; step < TT; ++step) {
        // ========== Phase A: h0 @ {Uz0,Ur0}^T, column t ==========
        float accz[BT], accr[BT];
        #pragma unroll
        for (int b = 0; b < BT; ++b) { accz[b] = 0.f; accr[b] = 0.f; }
        float4 wz = wbA[t], wr = wbA[256 + t];
        for (int k4 = 0; k4 < 64; ++k4) {
            float4 nz, nr;
            if (k4 < 63) {
                int base = (k4 + 1) * 512;
                nz = wbA[base + t]; nr = wbA[base + 256 + t];
            }
            #pragma unroll
            for (int b = 0; b < BT; ++b) {
                float4 a = *(const float4*)&h0[b][k4 * 4];
                accz[b] += a.x * wz.x + a.y * wz.y + a.z * wz.z + a.w * wz.w;
                accr[b] += a.x * wr.x + a.y * wr.y + a.z * wr.z + a.w * wr.w;
            }
            wz = nz; wr = nr;
        }
        // ---- z, r; write r*h0 (separate buffer, safe while others still read h0)
        float zv[BT], h0val[BT];
        #pragma unroll
        for (int b = 0; b < BT; ++b) {
            int c = xcls[b][step]; float m = xm[b][step];
            float z = sigf(accz[b] + m * wc[0] + az[0][c] + l0[0] * i0v[c]);
            float r = sigf(accr[b] + m * wc[1] + az[1][c] + l0[1] * i0v[c]);
            zv[b] = z; h0val[b] = h0[b][t];
            rh0[b][t] = r * h0val[b];
        }
        __syncthreads();   // rh0 visible; all phase-A reads of h0 done

        // ========== Phase B: (r∘h0) @ Uh0^T ==========
        float acch[BT];
        #pragma unroll
        for (int b = 0; b < BT; ++b) acch[b] = 0.f;
        float4 wh = wbH[t];
        for (int k4 = 0; k4 < 64; ++k4) {
            float4 nh;
            if (k4 < 63) nh = wbH[(k4 + 1) * 256 + t];
            #pragma unroll
            for (int b = 0; b < BT; ++b) {
                float4 a = *(const float4*)&rh0[b][k4 * 4];
                acch[b] += a.x * wh.x + a.y * wh.y + a.z * wh.z + a.w * wh.w;
            }
            wh = nh;
        }
        // ---- layer-0 h update (write h0: phase-B readers touch rh0 only)
        #pragma unroll
        for (int b = 0; b < BT; ++b) {
            int c = xcls[b][step]; float m = xm[b][step];
            float ht = tanhf(m * wc[2] + az[2][c] + acch[b] + l0[2] * i0v[c]);
            h0[b][t] = (1.f - zv[b]) * h0val[b] + zv[b] * ht;
        }
        __syncthreads();   // h0n visible

        // ========== Phase C: h0n @ {Wz1,Wr1,Wh1}^T + h1 @ {Uz1,Ur1}^T ==========
        float a2z[BT], a2r[BT], ahW[BT];
        #pragma unroll
        for (int b = 0; b < BT; ++b) { a2z[b] = 0.f; a2r[b] = 0.f; ahW[b] = 0.f; }
        float4 cz = wbC[t], cr = wbC[256 + t], ch = wbC[512 + t];
        float4 uz = wbC[768 + t], ur = wbC[1024 + t];
        for (int k4 = 0; k4 < 64; ++k4) {
            float4 ncz, ncr, nch, nuz, nur;
            if (k4 < 63) {
                int base = (k4 + 1) * 1280;
                ncz = wbC[base + t];        ncr = wbC[base + 256 + t];
                nch = wbC[base + 512 + t];  nuz = wbC[base + 768 + t];
                nur = wbC[base + 1024 + t];
            }
            #pragma unroll
            for (int b = 0; b < BT; ++b) {
                float4 a = *(const float4*)&h0[b][k4 * 4];
                float4 v = *(const float4*)&h1[b][k4 * 4];
                a2z[b] += a.x * cz.x + a.y * cz.y + a.z * cz.z + a.w * cz.w
                        + v.x * uz.x + v.y * uz.y + v.z * uz.z + v.w * uz.w;
                a2r[b] += a.x * cr.x + a.y * cr.y + a.z * cr.z + a.w * cr.w
                        + v.x * ur.x + v.y * ur.y + v.z * ur.z + v.w * ur.w;
                ahW[b] += a.x * ch.x + a.y * ch.y + a.z * ch.z + a.w * ch.w;
            }
            cz = ncz; cr = ncr; ch = nch; uz = nuz; ur = nur;
        }
        // ---- z1, r1; write r1*h1
        float z1v[BT], h1val[BT];
        #pragma unroll
        for (int b = 0; b < BT; ++b) {
            int c = xcls[b][step];
            float z1 = sigf(a2z[b] + b1c[0][c] + l1[0] * i1v[c]);
            float r1 = sigf(a2r[b] + b1c[1][c] + l1[1] * i1v[c]);
            z1v[b] = z1; h1val[b] = h1[b][t];
            rh1[b][t] = r1 * h1val[b];
        }
        __syncthreads();   // rh1 visible; all phase-C reads of h1 done

        // ========== Phase D: (r1∘h1) @ Uh1^T ==========
        float ahU[BT];
        #pragma unroll
        for (int b = 0; b < BT; ++b) ahU[b] = 0.f;
        wh = wbD[t];
        for (int k4 = 0; k4 < 64; ++k4) {
            float4 nh;
            if (k4 < 63) nh = wbD[(k4 + 1) * 256 + t];
            #pragma unroll
            for (int b = 0; b < BT; ++b) {
                float4 a = *(const float4*)&rh1[b][k4 * 4];
                ahU[b] += a.x * wh.x + a.y * wh.y + a.z * wh.z + a.w * wh.w;
            }
            wh = nh;
        }
        // ---- layer-1 h update
        #pragma unroll
        for (int b = 0; b < BT; ++b) {
            int c = xcls[b][step];
            float ht1 = tanhf(ahW[b] + b1c[2][c] + ahU[b] + l1[2] * i1v[c]);
            h1[b][t] = (1.f - z1v[b]) * h1val[b] + z1v[b] * ht1;
        }
        __syncthreads();   // h1 visible for next step
    }

    // ---- epilogue: out = h1 @ fc_w^T + fc_b
    if (t < BT * PP) {
        int b = t / PP, p = t - b * PP;
        float s = fcb[p];
        for (int h = 0; h < H; ++h) s += h1[b][h] * fcw[p * H + h];
        out[(size_t)(r0 + b) * PP + p] = s;
    }
}

extern "C" void kernel_launch(void* const* d_in, const int* in_sizes, int n_in,
                              void* d_out, int out_size, void* d_ws, size_t ws_size,
                              hipStream_t stream)
{
    const float* x   = (const float*)d_in[0];
    const float* emb = (const float*)d_in[1];
    const float* Wz0 = (const float*)d_in[2];  const float* Wr0 = (const float*)d_in[3];
    const float* Wh0 = (const float*)d_in[4];
    const float* Uz0 = (const float*)d_in[5];  const float* Ur0 = (const float*)d_in[6];
    const float* Uh0 = (const float*)d_in[7];
    const float* Vw0 = (const float*)d_in[8];  const float* Vb0 = (const float*)d_in[9];
    const float* lz0 = (const float*)d_in[10]; const float* lr0 = (const float*)d_in[11];
    const float* lh0 = (const float*)d_in[12];
    const float* Wz1 = (const float*)d_in[13]; const float* Wr1 = (const float*)d_in[14];
    const float* Wh1 = (const float*)d_in[15];
    const float* Uz1 = (const float*)d_in[16]; const float* Ur1 = (const float*)d_in[17];
    const float* Uh1 = (const float*)d_in[18];
    const float* Vw1 = (const float*)d_in[19]; const float* Vb1 = (const float*)d_in[20];
    const float* lz1 = (const float*)d_in[21]; const float* lr1 = (const float*)d_in[22];
    const float* lh1 = (const float*)d_in[23];
    const float* fcw = (const float*)d_in[24]; const float* fcb = (const float*)d_in[25];

    float*  ws  = (float*)d_ws;
    float4* wbA = (float4*)ws;                         //  32768 f4 = 131072 floats
    float4* wbH = (float4*)(ws + 131072);              //  16384 f4 =  65536 floats
    float4* wbC = (float4*)(ws + 196608);              //  81920 f4 = 327680 floats
    float4* wbD = (float4*)(ws + 524288);              //  16384 f4 =  65536 floats
    float*  cst = ws + 589824;                         //   8448 floats

    hipLaunchKernelGGL(pack_weights, dim3(576), dim3(256), 0, stream,
                       Uz0, Ur0, Uh0, Wz1, Wr1, Wh1, Uz1, Ur1, Uh1, wbA, wbH, wbC, wbD);
    hipLaunchKernelGGL(pack_consts, dim3(1), dim3(256), 0, stream,
                       Wz0, Wr0, Wh0, Vw0, Vb0, lz0, lr0, lh0,
                       Wz1, Wr1, Wh1, Vw1, Vb1, lz1, lr1, lh1, emb, cst);
    hipLaunchKernelGGL(trs_scan, dim3(2048 / BT), dim3(256), 0, stream,
                       x, wbA, wbH, wbC, wbD, cst, fcw, fcb, (float*)d_out);
}